// Round 1
// baseline (1903.764 us; speedup 1.0000x reference)
//
#include <hip/hip_runtime.h>
#include <cstdint>
#include <cstddef>

#define N_NODES   100000
#define N_EDGES   1600000
#define N_GRAPHS  64
#define HIDDEN    256
#define N_CLASSES 10
#define NEG_SLOPE 0.01f

// ---------------- degree / batch histograms ----------------
__global__ void k_deg_hist(const int* __restrict__ dst, int* __restrict__ cnt) {
    int e = blockIdx.x * 256 + threadIdx.x;
    if (e < N_EDGES) atomicAdd(&cnt[dst[e]], 1);
}

__global__ void k_batch_hist(const int* __restrict__ batch, int* __restrict__ gcnt) {
    int i = blockIdx.x * 256 + threadIdx.x;
    if (i < N_NODES) atomicAdd(&gcnt[batch[i]], 1);
}

__global__ void k_dinv(const int* __restrict__ cnt, float* __restrict__ dinv) {
    int i = blockIdx.x * 256 + threadIdx.x;
    if (i < N_NODES) dinv[i] = rsqrtf((float)cnt[i] + 1.0f);
}

// ---------------- exclusive scan of degree counts (CSR offsets) ----------------
// chunk = 1024 elements per block, 256 threads, 4 elements/thread
__global__ void k_scanA(const int* __restrict__ cnt, int* __restrict__ out, int* __restrict__ bsum) {
    __shared__ int sh[256];
    int tid = threadIdx.x;
    int base = blockIdx.x * 1024 + tid * 4;
    int v[4]; int s = 0;
#pragma unroll
    for (int i = 0; i < 4; i++) { int idx = base + i; v[i] = (idx < N_NODES) ? cnt[idx] : 0; s += v[i]; }
    sh[tid] = s; __syncthreads();
    for (int off = 1; off < 256; off <<= 1) {
        int t = (tid >= off) ? sh[tid - off] : 0;
        __syncthreads();
        sh[tid] += t;
        __syncthreads();
    }
    int excl = sh[tid] - s;
    if (tid == 255) bsum[blockIdx.x] = sh[255];
#pragma unroll
    for (int i = 0; i < 4; i++) { int idx = base + i; if (idx < N_NODES) out[idx] = excl; excl += v[i]; }
}

__global__ void k_scanB(int* __restrict__ bsum, int nb) {
    __shared__ int sh[128];
    int tid = threadIdx.x;
    int v = (tid < nb) ? bsum[tid] : 0;
    sh[tid] = v; __syncthreads();
    for (int off = 1; off < 128; off <<= 1) {
        int t = (tid >= off) ? sh[tid - off] : 0;
        __syncthreads();
        sh[tid] += t;
        __syncthreads();
    }
    if (tid < nb) bsum[tid] = sh[tid] - v;  // exclusive
}

__global__ void k_scanC(int* __restrict__ off_arr, const int* __restrict__ bsum, int* __restrict__ cursor) {
    int i = blockIdx.x * 256 + threadIdx.x;
    if (i < N_NODES) {
        int v = off_arr[i] + bsum[i >> 10];
        off_arr[i] = v;
        cursor[i]  = v;
        if (i == 0) off_arr[N_NODES] = N_EDGES;
    }
}

// ---------------- CSR fill (sorted by dst) + per-edge coefficient ----------------
__global__ void k_fill(const int* __restrict__ src, const int* __restrict__ dst,
                       const float* __restrict__ dinv, int* __restrict__ cursor,
                       int* __restrict__ csrc, float* __restrict__ ccoef) {
    int e = blockIdx.x * 256 + threadIdx.x;
    if (e < N_EDGES) {
        int d = dst[e], s = src[e];
        int p = atomicAdd(&cursor[d], 1);
        csrc[p]  = s;
        ccoef[p] = dinv[s] * dinv[d];
    }
}

__global__ void k_gscan(const int* __restrict__ gcnt, int* __restrict__ gstart) {
    __shared__ int sh[64];
    int t = threadIdx.x;
    int v = gcnt[t]; sh[t] = v; __syncthreads();
    for (int off = 1; off < 64; off <<= 1) {
        int x = (t >= off) ? sh[t - off] : 0;
        __syncthreads();
        sh[t] += x;
        __syncthreads();
    }
    gstart[t] = sh[t] - v;
}

// ---------------- layer-1 matmul: [N,3] @ [3,256] ----------------
__global__ void k_mm1(const float* __restrict__ x, const float* __restrict__ W1, float* __restrict__ out) {
    int node = blockIdx.x; int c = threadIdx.x;
    float x0 = x[node * 3 + 0], x1 = x[node * 3 + 1], x2 = x[node * 3 + 2];
    out[(size_t)node * HIDDEN + c] = x0 * W1[c] + x1 * W1[HIDDEN + c] + x2 * W1[2 * HIDDEN + c];
}

// ---------------- SGEMM: [M,256] @ [256,256], BM=BN=64, BK=16, 4x4/thread ----------------
__global__ __launch_bounds__(256) void k_gemm256(const float* __restrict__ A,
                                                 const float* __restrict__ B,
                                                 float* __restrict__ C, int M) {
    __shared__ float As[16][68];
    __shared__ float Bs[16][68];
    int tid = threadIdx.x;
    int m0 = blockIdx.x * 64;
    int n0 = blockIdx.y * 64;
    int tx = tid & 15, ty = tid >> 4;
    float acc[4][4] = {};
    int ar = tid >> 2;          // 0..63  (A row within tile)
    int ak = (tid & 3) * 4;     // 0,4,8,12
    int bk = tid >> 4;          // 0..15  (B row within tile)
    int bn = (tid & 15) * 4;    // 0..60
    for (int k0 = 0; k0 < 256; k0 += 16) {
        float4 av = make_float4(0.f, 0.f, 0.f, 0.f);
        int m = m0 + ar;
        if (m < M) av = *(const float4*)(A + (size_t)m * 256 + k0 + ak);
        As[ak + 0][ar] = av.x; As[ak + 1][ar] = av.y; As[ak + 2][ar] = av.z; As[ak + 3][ar] = av.w;
        float4 bv = *(const float4*)(B + (size_t)(k0 + bk) * 256 + n0 + bn);
        *(float4*)&Bs[bk][bn] = bv;
        __syncthreads();
#pragma unroll
        for (int k = 0; k < 16; k++) {
            float a[4], b[4];
            *(float4*)a = *(const float4*)&As[k][ty * 4];
            *(float4*)b = *(const float4*)&Bs[k][tx * 4];
#pragma unroll
            for (int i = 0; i < 4; i++)
#pragma unroll
                for (int j = 0; j < 4; j++)
                    acc[i][j] += a[i] * b[j];
        }
        __syncthreads();
    }
#pragma unroll
    for (int i = 0; i < 4; i++) {
        int m = m0 + ty * 4 + i;
        if (m < M) {
            *(float4*)(C + (size_t)m * 256 + n0 + tx * 4) =
                make_float4(acc[i][0], acc[i][1], acc[i][2], acc[i][3]);
        }
    }
}

// ---------------- fused aggregation + self-loop + bias + leaky-relu ----------------
// one wave per node, lane = 4 contiguous floats (float4)
__global__ __launch_bounds__(256) void k_agg(const float* __restrict__ h, const float* __restrict__ bias,
                                             const int* __restrict__ off, const int* __restrict__ csrc,
                                             const float* __restrict__ ccoef, const float* __restrict__ dinv,
                                             float* __restrict__ out) {
    int node = (blockIdx.x * 256 + threadIdx.x) >> 6;
    int lane = threadIdx.x & 63;
    if (node >= N_NODES) return;
    float di = dinv[node];
    float selfc = di * di;
    float4 hv = ((const float4*)(h + (size_t)node * HIDDEN))[lane];
    float4 bv = ((const float4*)bias)[lane];
    float4 acc = make_float4(bv.x + hv.x * selfc, bv.y + hv.y * selfc,
                             bv.z + hv.z * selfc, bv.w + hv.w * selfc);
    int e = off[node], e1 = off[node + 1];
    for (; e + 1 < e1; e += 2) {
        int s0 = csrc[e], s1 = csrc[e + 1];
        float c0 = ccoef[e], c1 = ccoef[e + 1];
        float4 v0 = ((const float4*)(h + (size_t)s0 * HIDDEN))[lane];
        float4 v1 = ((const float4*)(h + (size_t)s1 * HIDDEN))[lane];
        acc.x += c0 * v0.x + c1 * v1.x;
        acc.y += c0 * v0.y + c1 * v1.y;
        acc.z += c0 * v0.z + c1 * v1.z;
        acc.w += c0 * v0.w + c1 * v1.w;
    }
    if (e < e1) {
        int s0 = csrc[e]; float c0 = ccoef[e];
        float4 v0 = ((const float4*)(h + (size_t)s0 * HIDDEN))[lane];
        acc.x += c0 * v0.x; acc.y += c0 * v0.y; acc.z += c0 * v0.z; acc.w += c0 * v0.w;
    }
    acc.x = acc.x >= 0.f ? acc.x : NEG_SLOPE * acc.x;
    acc.y = acc.y >= 0.f ? acc.y : NEG_SLOPE * acc.y;
    acc.z = acc.z >= 0.f ? acc.z : NEG_SLOPE * acc.z;
    acc.w = acc.w >= 0.f ? acc.w : NEG_SLOPE * acc.w;
    ((float4*)(out + (size_t)node * HIDDEN))[lane] = acc;
}

// ---------------- global mean pool (partial sums + atomics) ----------------
__global__ void k_pool(const float* __restrict__ h, const int* __restrict__ gstart,
                       const int* __restrict__ gcnt, float* __restrict__ pooled) {
    int g = blockIdx.x, chunk = blockIdx.y, t = threadIdx.x;
    int s = gstart[g], c = gcnt[g];
    int i0 = s + (int)(((long long)c * chunk) / 16);
    int i1 = s + (int)(((long long)c * (chunk + 1)) / 16);
    float acc = 0.f;
    for (int i = i0; i < i1; ++i) acc += h[(size_t)i * HIDDEN + t];
    atomicAdd(&pooled[g * HIDDEN + t], acc);
}

// ---------------- classifier head + softmax (one wave per graph) ----------------
__global__ void k_head(const float* __restrict__ pooled, const int* __restrict__ gcnt,
                       const float* __restrict__ Wc, const float* __restrict__ bc,
                       float* __restrict__ out) {
    int g = blockIdx.x; int l = threadIdx.x;  // 64 threads
    float inv = 1.0f / fmaxf((float)gcnt[g], 1.0f);
    float p[4];
#pragma unroll
    for (int i = 0; i < 4; i++) p[i] = pooled[g * HIDDEN + l + i * 64] * inv;
    __shared__ float logits[N_CLASSES];
#pragma unroll
    for (int j = 0; j < N_CLASSES; j++) {
        float s = 0.f;
#pragma unroll
        for (int i = 0; i < 4; i++) s += p[i] * Wc[(l + i * 64) * N_CLASSES + j];
        for (int o = 32; o > 0; o >>= 1) s += __shfl_down(s, o, 64);
        if (l == 0) logits[j] = s + bc[j];
    }
    __syncthreads();
    if (l == 0) {
        float m = logits[0];
        for (int j = 1; j < N_CLASSES; j++) m = fmaxf(m, logits[j]);
        float e[N_CLASSES]; float sum = 0.f;
        for (int j = 0; j < N_CLASSES; j++) { e[j] = expf(logits[j] - m); sum += e[j]; }
        for (int j = 0; j < N_CLASSES; j++) out[g * N_CLASSES + j] = e[j] / sum;
    }
}

extern "C" void kernel_launch(void* const* d_in, const int* in_sizes, int n_in,
                              void* d_out, int out_size, void* d_ws, size_t ws_size,
                              hipStream_t stream) {
    const float* x     = (const float*)d_in[0];
    const int*   edge  = (const int*)d_in[1];
    const int*   batch = (const int*)d_in[2];
    const float* W1 = (const float*)d_in[3];
    const float* b1 = (const float*)d_in[4];
    const float* W2 = (const float*)d_in[5];
    const float* b2 = (const float*)d_in[6];
    const float* W3 = (const float*)d_in[7];
    const float* b3 = (const float*)d_in[8];
    const float* Wc = (const float*)d_in[9];
    const float* bc = (const float*)d_in[10];
    float* out = (float*)d_out;
    const int* srcp = edge;
    const int* dstp = edge + N_EDGES;

    char* ws = (char*)d_ws;
    size_t off = 0;
    auto alloc = [&](size_t bytes) -> char* {
        char* p = ws + off;
        off += (bytes + 255) & ~(size_t)255;
        return p;
    };
    float* hA       = (float*)alloc((size_t)N_NODES * HIDDEN * 4);
    float* hB       = (float*)alloc((size_t)N_NODES * HIDDEN * 4);
    int*   deg_cnt  = (int*)alloc((size_t)N_NODES * 4);
    float* dinv     = (float*)alloc((size_t)N_NODES * 4);
    int*   csr_off  = (int*)alloc((size_t)(N_NODES + 1) * 4);
    int*   cursor   = (int*)alloc((size_t)N_NODES * 4);
    int*   csr_src  = (int*)alloc((size_t)N_EDGES * 4);
    float* csr_coef = (float*)alloc((size_t)N_EDGES * 4);
    int*   gcnt     = (int*)alloc((size_t)N_GRAPHS * 4);
    int*   gstart   = (int*)alloc((size_t)N_GRAPHS * 4);
    float* pooled   = (float*)alloc((size_t)N_GRAPHS * HIDDEN * 4);
    int*   bsum     = (int*)alloc(128 * 4);

    hipMemsetAsync(deg_cnt, 0, (size_t)N_NODES * 4, stream);
    hipMemsetAsync(gcnt, 0, (size_t)N_GRAPHS * 4, stream);
    hipMemsetAsync(pooled, 0, (size_t)N_GRAPHS * HIDDEN * 4, stream);

    int eb = (N_EDGES + 255) / 256;
    int nb = (N_NODES + 255) / 256;
    int sblocks = (N_NODES + 1023) / 1024;  // 98

    k_deg_hist<<<eb, 256, 0, stream>>>(dstp, deg_cnt);
    k_batch_hist<<<nb, 256, 0, stream>>>(batch, gcnt);
    k_dinv<<<nb, 256, 0, stream>>>(deg_cnt, dinv);
    k_scanA<<<sblocks, 256, 0, stream>>>(deg_cnt, csr_off, bsum);
    k_scanB<<<1, 128, 0, stream>>>(bsum, sblocks);
    k_scanC<<<nb, 256, 0, stream>>>(csr_off, bsum, cursor);
    k_fill<<<eb, 256, 0, stream>>>(srcp, dstp, dinv, cursor, csr_src, csr_coef);
    k_gscan<<<1, 64, 0, stream>>>(gcnt, gstart);

    // layer 1
    k_mm1<<<N_NODES, 256, 0, stream>>>(x, W1, hA);
    int aggb = (N_NODES + 3) / 4;
    k_agg<<<aggb, 256, 0, stream>>>(hA, b1, csr_off, csr_src, csr_coef, dinv, hB);
    // layer 2
    dim3 gg((N_NODES + 63) / 64, 4);
    k_gemm256<<<gg, 256, 0, stream>>>(hB, W2, hA, N_NODES);
    k_agg<<<aggb, 256, 0, stream>>>(hA, b2, csr_off, csr_src, csr_coef, dinv, hB);
    // layer 3
    k_gemm256<<<gg, 256, 0, stream>>>(hB, W3, hA, N_NODES);
    k_agg<<<aggb, 256, 0, stream>>>(hA, b3, csr_off, csr_src, csr_coef, dinv, hB);
    // pool + head
    dim3 pg(N_GRAPHS, 16);
    k_pool<<<pg, 256, 0, stream>>>(hB, gstart, gcnt, pooled);
    k_head<<<N_GRAPHS, 64, 0, stream>>>(pooled, gcnt, Wc, bc, out);
}

// Round 2
// 1404.983 us; speedup vs baseline: 1.3550x; 1.3550x over previous
//
#include <hip/hip_runtime.h>
#include <cstdint>
#include <cstddef>

#define N_NODES   100000
#define N_EDGES   1600000
#define N_GRAPHS  64
#define HIDDEN    256
#define N_CLASSES 10
#define NEG_SLOPE 0.01f

// ---------------- degree histogram ----------------
__global__ void k_deg_hist(const int* __restrict__ dst, int* __restrict__ cnt) {
    int e = blockIdx.x * 256 + threadIdx.x;
    if (e < N_EDGES) atomicAdd(&cnt[dst[e]], 1);
}

// ---------------- graph boundaries via binary search (batch is sorted) ----------------
__global__ void k_graph_bounds(const int* __restrict__ batch,
                               int* __restrict__ gstart, int* __restrict__ gcnt) {
    int g = threadIdx.x;  // 0..63
    int lo = 0, hi = N_NODES;
    while (lo < hi) { int mid = (lo + hi) >> 1; if (batch[mid] < g) lo = mid + 1; else hi = mid; }
    __shared__ int sh[N_GRAPHS + 1];
    sh[g] = lo;
    if (g == 0) sh[N_GRAPHS] = N_NODES;
    __syncthreads();
    gstart[g] = sh[g];
    gcnt[g]   = sh[g + 1] - sh[g];
}

__global__ void k_dinv(const int* __restrict__ cnt, float* __restrict__ dinv) {
    int i = blockIdx.x * 256 + threadIdx.x;
    if (i < N_NODES) dinv[i] = rsqrtf((float)cnt[i] + 1.0f);
}

// ---------------- exclusive scan of degree counts (CSR offsets) ----------------
// chunk = 1024 elements per block, 256 threads, 4 elements/thread
__global__ void k_scanA(const int* __restrict__ cnt, int* __restrict__ out, int* __restrict__ bsum) {
    __shared__ int sh[256];
    int tid = threadIdx.x;
    int base = blockIdx.x * 1024 + tid * 4;
    int v[4]; int s = 0;
#pragma unroll
    for (int i = 0; i < 4; i++) { int idx = base + i; v[i] = (idx < N_NODES) ? cnt[idx] : 0; s += v[i]; }
    sh[tid] = s; __syncthreads();
    for (int off = 1; off < 256; off <<= 1) {
        int t = (tid >= off) ? sh[tid - off] : 0;
        __syncthreads();
        sh[tid] += t;
        __syncthreads();
    }
    int excl = sh[tid] - s;
    if (tid == 255) bsum[blockIdx.x] = sh[255];
#pragma unroll
    for (int i = 0; i < 4; i++) { int idx = base + i; if (idx < N_NODES) out[idx] = excl; excl += v[i]; }
}

__global__ void k_scanB(int* __restrict__ bsum, int nb) {
    __shared__ int sh[128];
    int tid = threadIdx.x;
    int v = (tid < nb) ? bsum[tid] : 0;
    sh[tid] = v; __syncthreads();
    for (int off = 1; off < 128; off <<= 1) {
        int t = (tid >= off) ? sh[tid - off] : 0;
        __syncthreads();
        sh[tid] += t;
        __syncthreads();
    }
    if (tid < nb) bsum[tid] = sh[tid] - v;  // exclusive
}

__global__ void k_scanC(int* __restrict__ off_arr, const int* __restrict__ bsum, int* __restrict__ cursor) {
    int i = blockIdx.x * 256 + threadIdx.x;
    if (i < N_NODES) {
        int v = off_arr[i] + bsum[i >> 10];
        off_arr[i] = v;
        cursor[i]  = v;
        if (i == 0) off_arr[N_NODES] = N_EDGES;
    }
}

// ---------------- CSR fill (sorted by dst) + per-edge coefficient ----------------
__global__ void k_fill(const int* __restrict__ src, const int* __restrict__ dst,
                       const float* __restrict__ dinv, int* __restrict__ cursor,
                       int* __restrict__ csrc, float* __restrict__ ccoef) {
    int e = blockIdx.x * 256 + threadIdx.x;
    if (e < N_EDGES) {
        int d = dst[e], s = src[e];
        int p = atomicAdd(&cursor[d], 1);
        csrc[p]  = s;
        ccoef[p] = dinv[s] * dinv[d];
    }
}

// ---------------- layer-1 matmul: [N,3] @ [3,256] ----------------
__global__ void k_mm1(const float* __restrict__ x, const float* __restrict__ W1, float* __restrict__ out) {
    int node = blockIdx.x; int c = threadIdx.x;
    float x0 = x[node * 3 + 0], x1 = x[node * 3 + 1], x2 = x[node * 3 + 2];
    out[(size_t)node * HIDDEN + c] = x0 * W1[c] + x1 * W1[HIDDEN + c] + x2 * W1[2 * HIDDEN + c];
}

// ---------------- SGEMM: [M,256] @ [256,256], BM=BN=64, BK=16, 4x4/thread ----------------
__global__ __launch_bounds__(256) void k_gemm256(const float* __restrict__ A,
                                                 const float* __restrict__ B,
                                                 float* __restrict__ C, int M) {
    __shared__ float As[16][68];
    __shared__ float Bs[16][68];
    int tid = threadIdx.x;
    int m0 = blockIdx.x * 64;
    int n0 = blockIdx.y * 64;
    int tx = tid & 15, ty = tid >> 4;
    float acc[4][4] = {};
    int ar = tid >> 2;          // 0..63  (A row within tile)
    int ak = (tid & 3) * 4;     // 0,4,8,12
    int bk = tid >> 4;          // 0..15  (B row within tile)
    int bn = (tid & 15) * 4;    // 0..60
    for (int k0 = 0; k0 < 256; k0 += 16) {
        float4 av = make_float4(0.f, 0.f, 0.f, 0.f);
        int m = m0 + ar;
        if (m < M) av = *(const float4*)(A + (size_t)m * 256 + k0 + ak);
        As[ak + 0][ar] = av.x; As[ak + 1][ar] = av.y; As[ak + 2][ar] = av.z; As[ak + 3][ar] = av.w;
        float4 bv = *(const float4*)(B + (size_t)(k0 + bk) * 256 + n0 + bn);
        *(float4*)&Bs[bk][bn] = bv;
        __syncthreads();
#pragma unroll
        for (int k = 0; k < 16; k++) {
            float a[4], b[4];
            *(float4*)a = *(const float4*)&As[k][ty * 4];
            *(float4*)b = *(const float4*)&Bs[k][tx * 4];
#pragma unroll
            for (int i = 0; i < 4; i++)
#pragma unroll
                for (int j = 0; j < 4; j++)
                    acc[i][j] += a[i] * b[j];
        }
        __syncthreads();
    }
#pragma unroll
    for (int i = 0; i < 4; i++) {
        int m = m0 + ty * 4 + i;
        if (m < M) {
            *(float4*)(C + (size_t)m * 256 + n0 + tx * 4) =
                make_float4(acc[i][0], acc[i][1], acc[i][2], acc[i][3]);
        }
    }
}

// ---------------- fused aggregation + self-loop + bias + leaky-relu ----------------
// one wave per node, lane = 4 contiguous floats (float4)
__global__ __launch_bounds__(256) void k_agg(const float* __restrict__ h, const float* __restrict__ bias,
                                             const int* __restrict__ off, const int* __restrict__ csrc,
                                             const float* __restrict__ ccoef, const float* __restrict__ dinv,
                                             float* __restrict__ out) {
    int node = (blockIdx.x * 256 + threadIdx.x) >> 6;
    int lane = threadIdx.x & 63;
    if (node >= N_NODES) return;
    float di = dinv[node];
    float selfc = di * di;
    float4 hv = ((const float4*)(h + (size_t)node * HIDDEN))[lane];
    float4 bv = ((const float4*)bias)[lane];
    float4 acc = make_float4(bv.x + hv.x * selfc, bv.y + hv.y * selfc,
                             bv.z + hv.z * selfc, bv.w + hv.w * selfc);
    int e = off[node], e1 = off[node + 1];
    for (; e + 1 < e1; e += 2) {
        int s0 = csrc[e], s1 = csrc[e + 1];
        float c0 = ccoef[e], c1 = ccoef[e + 1];
        float4 v0 = ((const float4*)(h + (size_t)s0 * HIDDEN))[lane];
        float4 v1 = ((const float4*)(h + (size_t)s1 * HIDDEN))[lane];
        acc.x += c0 * v0.x + c1 * v1.x;
        acc.y += c0 * v0.y + c1 * v1.y;
        acc.z += c0 * v0.z + c1 * v1.z;
        acc.w += c0 * v0.w + c1 * v1.w;
    }
    if (e < e1) {
        int s0 = csrc[e]; float c0 = ccoef[e];
        float4 v0 = ((const float4*)(h + (size_t)s0 * HIDDEN))[lane];
        acc.x += c0 * v0.x; acc.y += c0 * v0.y; acc.z += c0 * v0.z; acc.w += c0 * v0.w;
    }
    acc.x = acc.x >= 0.f ? acc.x : NEG_SLOPE * acc.x;
    acc.y = acc.y >= 0.f ? acc.y : NEG_SLOPE * acc.y;
    acc.z = acc.z >= 0.f ? acc.z : NEG_SLOPE * acc.z;
    acc.w = acc.w >= 0.f ? acc.w : NEG_SLOPE * acc.w;
    ((float4*)(out + (size_t)node * HIDDEN))[lane] = acc;
}

// ---------------- global mean pool (partial sums + atomics) ----------------
__global__ void k_pool(const float* __restrict__ h, const int* __restrict__ gstart,
                       const int* __restrict__ gcnt, float* __restrict__ pooled) {
    int g = blockIdx.x, chunk = blockIdx.y, t = threadIdx.x;
    int s = gstart[g], c = gcnt[g];
    int i0 = s + (int)(((long long)c * chunk) / 16);
    int i1 = s + (int)(((long long)c * (chunk + 1)) / 16);
    float acc = 0.f;
    for (int i = i0; i < i1; ++i) acc += h[(size_t)i * HIDDEN + t];
    atomicAdd(&pooled[g * HIDDEN + t], acc);
}

// ---------------- classifier head + softmax (one wave per graph) ----------------
__global__ void k_head(const float* __restrict__ pooled, const int* __restrict__ gcnt,
                       const float* __restrict__ Wc, const float* __restrict__ bc,
                       float* __restrict__ out) {
    int g = blockIdx.x; int l = threadIdx.x;  // 64 threads
    float inv = 1.0f / fmaxf((float)gcnt[g], 1.0f);
    float p[4];
#pragma unroll
    for (int i = 0; i < 4; i++) p[i] = pooled[g * HIDDEN + l + i * 64] * inv;
    __shared__ float logits[N_CLASSES];
#pragma unroll
    for (int j = 0; j < N_CLASSES; j++) {
        float s = 0.f;
#pragma unroll
        for (int i = 0; i < 4; i++) s += p[i] * Wc[(l + i * 64) * N_CLASSES + j];
        for (int o = 32; o > 0; o >>= 1) s += __shfl_down(s, o, 64);
        if (l == 0) logits[j] = s + bc[j];
    }
    __syncthreads();
    if (l == 0) {
        float m = logits[0];
        for (int j = 1; j < N_CLASSES; j++) m = fmaxf(m, logits[j]);
        float e[N_CLASSES]; float sum = 0.f;
        for (int j = 0; j < N_CLASSES; j++) { e[j] = expf(logits[j] - m); sum += e[j]; }
        for (int j = 0; j < N_CLASSES; j++) out[g * N_CLASSES + j] = e[j] / sum;
    }
}

extern "C" void kernel_launch(void* const* d_in, const int* in_sizes, int n_in,
                              void* d_out, int out_size, void* d_ws, size_t ws_size,
                              hipStream_t stream) {
    const float* x     = (const float*)d_in[0];
    const int*   edge  = (const int*)d_in[1];
    const int*   batch = (const int*)d_in[2];
    const float* W1 = (const float*)d_in[3];
    const float* b1 = (const float*)d_in[4];
    const float* W2 = (const float*)d_in[5];
    const float* b2 = (const float*)d_in[6];
    const float* W3 = (const float*)d_in[7];
    const float* b3 = (const float*)d_in[8];
    const float* Wc = (const float*)d_in[9];
    const float* bc = (const float*)d_in[10];
    float* out = (float*)d_out;
    const int* srcp = edge;
    const int* dstp = edge + N_EDGES;

    char* ws = (char*)d_ws;
    size_t off = 0;
    auto alloc = [&](size_t bytes) -> char* {
        char* p = ws + off;
        off += (bytes + 255) & ~(size_t)255;
        return p;
    };
    float* hA       = (float*)alloc((size_t)N_NODES * HIDDEN * 4);
    float* hB       = (float*)alloc((size_t)N_NODES * HIDDEN * 4);
    int*   deg_cnt  = (int*)alloc((size_t)N_NODES * 4);
    float* dinv     = (float*)alloc((size_t)N_NODES * 4);
    int*   csr_off  = (int*)alloc((size_t)(N_NODES + 1) * 4);
    int*   cursor   = (int*)alloc((size_t)N_NODES * 4);
    int*   csr_src  = (int*)alloc((size_t)N_EDGES * 4);
    float* csr_coef = (float*)alloc((size_t)N_EDGES * 4);
    int*   gcnt     = (int*)alloc((size_t)N_GRAPHS * 4);
    int*   gstart   = (int*)alloc((size_t)N_GRAPHS * 4);
    float* pooled   = (float*)alloc((size_t)N_GRAPHS * HIDDEN * 4);
    int*   bsum     = (int*)alloc(128 * 4);

    hipMemsetAsync(deg_cnt, 0, (size_t)N_NODES * 4, stream);
    hipMemsetAsync(pooled, 0, (size_t)N_GRAPHS * HIDDEN * 4, stream);

    int eb = (N_EDGES + 255) / 256;
    int nb = (N_NODES + 255) / 256;
    int sblocks = (N_NODES + 1023) / 1024;  // 98

    k_deg_hist<<<eb, 256, 0, stream>>>(dstp, deg_cnt);
    k_graph_bounds<<<1, 64, 0, stream>>>(batch, gstart, gcnt);
    k_dinv<<<nb, 256, 0, stream>>>(deg_cnt, dinv);
    k_scanA<<<sblocks, 256, 0, stream>>>(deg_cnt, csr_off, bsum);
    k_scanB<<<1, 128, 0, stream>>>(bsum, sblocks);
    k_scanC<<<nb, 256, 0, stream>>>(csr_off, bsum, cursor);
    k_fill<<<eb, 256, 0, stream>>>(srcp, dstp, dinv, cursor, csr_src, csr_coef);

    // layer 1
    k_mm1<<<N_NODES, 256, 0, stream>>>(x, W1, hA);
    int aggb = (N_NODES + 3) / 4;
    k_agg<<<aggb, 256, 0, stream>>>(hA, b1, csr_off, csr_src, csr_coef, dinv, hB);
    // layer 2
    dim3 gg((N_NODES + 63) / 64, 4);
    k_gemm256<<<gg, 256, 0, stream>>>(hB, W2, hA, N_NODES);
    k_agg<<<aggb, 256, 0, stream>>>(hA, b2, csr_off, csr_src, csr_coef, dinv, hB);
    // layer 3
    k_gemm256<<<gg, 256, 0, stream>>>(hB, W3, hA, N_NODES);
    k_agg<<<aggb, 256, 0, stream>>>(hA, b3, csr_off, csr_src, csr_coef, dinv, hB);
    // pool + head
    dim3 pg(N_GRAPHS, 16);
    k_pool<<<pg, 256, 0, stream>>>(hB, gstart, gcnt, pooled);
    k_head<<<N_GRAPHS, 64, 0, stream>>>(pooled, gcnt, Wc, bc, out);
}

// Round 3
// 1072.352 us; speedup vs baseline: 1.7753x; 1.3102x over previous
//
#include <hip/hip_runtime.h>
#include <hip/hip_bf16.h>
#include <cstdint>
#include <cstddef>

#define N_NODES   100000
#define N_EDGES   1600000
#define N_GRAPHS  64
#define HIDDEN    256
#define N_CLASSES 10
#define NEG_SLOPE 0.01f

__device__ __forceinline__ float bf2f(unsigned short u) {
    return __uint_as_float(((unsigned int)u) << 16);
}

// ---------------- degree histogram ----------------
__global__ void k_deg_hist(const int* __restrict__ dst, int* __restrict__ cnt) {
    int e = blockIdx.x * 256 + threadIdx.x;
    if (e < N_EDGES) atomicAdd(&cnt[dst[e]], 1);
}

// ---------------- graph boundaries via binary search (batch is sorted) ----------------
__global__ void k_graph_bounds(const int* __restrict__ batch,
                               int* __restrict__ gstart, int* __restrict__ gcnt) {
    int g = threadIdx.x;  // 0..63
    int lo = 0, hi = N_NODES;
    while (lo < hi) { int mid = (lo + hi) >> 1; if (batch[mid] < g) lo = mid + 1; else hi = mid; }
    __shared__ int sh[N_GRAPHS + 1];
    sh[g] = lo;
    if (g == 0) sh[N_GRAPHS] = N_NODES;
    __syncthreads();
    gstart[g] = sh[g];
    gcnt[g]   = sh[g + 1] - sh[g];
}

__global__ void k_dinv(const int* __restrict__ cnt, float* __restrict__ dinv) {
    int i = blockIdx.x * 256 + threadIdx.x;
    if (i < N_NODES) dinv[i] = rsqrtf((float)cnt[i] + 1.0f);
}

// ---------------- exclusive scan of degree counts (CSR offsets) ----------------
__global__ void k_scanA(const int* __restrict__ cnt, int* __restrict__ out, int* __restrict__ bsum) {
    __shared__ int sh[256];
    int tid = threadIdx.x;
    int base = blockIdx.x * 1024 + tid * 4;
    int v[4]; int s = 0;
#pragma unroll
    for (int i = 0; i < 4; i++) { int idx = base + i; v[i] = (idx < N_NODES) ? cnt[idx] : 0; s += v[i]; }
    sh[tid] = s; __syncthreads();
    for (int off = 1; off < 256; off <<= 1) {
        int t = (tid >= off) ? sh[tid - off] : 0;
        __syncthreads();
        sh[tid] += t;
        __syncthreads();
    }
    int excl = sh[tid] - s;
    if (tid == 255) bsum[blockIdx.x] = sh[255];
#pragma unroll
    for (int i = 0; i < 4; i++) { int idx = base + i; if (idx < N_NODES) out[idx] = excl; excl += v[i]; }
}

__global__ void k_scanB(int* __restrict__ bsum, int nb) {
    __shared__ int sh[128];
    int tid = threadIdx.x;
    int v = (tid < nb) ? bsum[tid] : 0;
    sh[tid] = v; __syncthreads();
    for (int off = 1; off < 128; off <<= 1) {
        int t = (tid >= off) ? sh[tid - off] : 0;
        __syncthreads();
        sh[tid] += t;
        __syncthreads();
    }
    if (tid < nb) bsum[tid] = sh[tid] - v;  // exclusive
}

__global__ void k_scanC(int* __restrict__ off_arr, const int* __restrict__ bsum, int* __restrict__ cursor) {
    int i = blockIdx.x * 256 + threadIdx.x;
    if (i < N_NODES) {
        int v = off_arr[i] + bsum[i >> 10];
        off_arr[i] = v;
        cursor[i]  = v;
        if (i == 0) off_arr[N_NODES] = N_EDGES;
    }
}

// ---------------- CSR fill (sorted by dst) + per-edge coefficient ----------------
__global__ void k_fill(const int* __restrict__ src, const int* __restrict__ dst,
                       const float* __restrict__ dinv, int* __restrict__ cursor,
                       int* __restrict__ csrc, float* __restrict__ ccoef) {
    int e = blockIdx.x * 256 + threadIdx.x;
    if (e < N_EDGES) {
        int d = dst[e], s = src[e];
        int p = atomicAdd(&cursor[d], 1);
        csrc[p]  = s;
        ccoef[p] = dinv[s] * dinv[d];
    }
}

// ---------------- layer-1 matmul: [N,3] @ [3,256], bf16 output ----------------
__global__ void k_mm1(const float* __restrict__ x, const float* __restrict__ W1,
                      __hip_bfloat16* __restrict__ out) {
    int node = blockIdx.x; int c = threadIdx.x;
    float x0 = x[node * 3 + 0], x1 = x[node * 3 + 1], x2 = x[node * 3 + 2];
    float v = x0 * W1[c] + x1 * W1[HIDDEN + c] + x2 * W1[2 * HIDDEN + c];
    out[(size_t)node * HIDDEN + c] = __float2bfloat16(v);
}

// ---------------- SGEMM: [M,256] @ [256,256], fp32 math, bf16 C-store ----------------
__global__ __launch_bounds__(256) void k_gemm256(const float* __restrict__ A,
                                                 const float* __restrict__ B,
                                                 __hip_bfloat16* __restrict__ C, int M) {
    __shared__ float As[16][68];
    __shared__ float Bs[16][68];
    int tid = threadIdx.x;
    int m0 = blockIdx.x * 64;
    int n0 = blockIdx.y * 64;
    int tx = tid & 15, ty = tid >> 4;
    float acc[4][4] = {};
    int ar = tid >> 2;          // 0..63  (A row within tile)
    int ak = (tid & 3) * 4;     // 0,4,8,12
    int bk = tid >> 4;          // 0..15  (B row within tile)
    int bn = (tid & 15) * 4;    // 0..60
    for (int k0 = 0; k0 < 256; k0 += 16) {
        float4 av = make_float4(0.f, 0.f, 0.f, 0.f);
        int m = m0 + ar;
        if (m < M) av = *(const float4*)(A + (size_t)m * 256 + k0 + ak);
        As[ak + 0][ar] = av.x; As[ak + 1][ar] = av.y; As[ak + 2][ar] = av.z; As[ak + 3][ar] = av.w;
        float4 bv = *(const float4*)(B + (size_t)(k0 + bk) * 256 + n0 + bn);
        *(float4*)&Bs[bk][bn] = bv;
        __syncthreads();
#pragma unroll
        for (int k = 0; k < 16; k++) {
            float a[4], b[4];
            *(float4*)a = *(const float4*)&As[k][ty * 4];
            *(float4*)b = *(const float4*)&Bs[k][tx * 4];
#pragma unroll
            for (int i = 0; i < 4; i++)
#pragma unroll
                for (int j = 0; j < 4; j++)
                    acc[i][j] += a[i] * b[j];
        }
        __syncthreads();
    }
#pragma unroll
    for (int i = 0; i < 4; i++) {
        int m = m0 + ty * 4 + i;
        if (m < M) {
            __hip_bfloat16 pk[4];
#pragma unroll
            for (int j = 0; j < 4; j++) pk[j] = __float2bfloat16(acc[i][j]);
            *(uint2*)(C + (size_t)m * 256 + n0 + tx * 4) = *(uint2*)pk;
        }
    }
}

// ---------------- fused aggregation + self-loop + bias + leaky-relu ----------------
// one wave per node; h rows are bf16 (512 B); lane = 4 contiguous bf16 (8 B)
__global__ __launch_bounds__(256) void k_agg(const __hip_bfloat16* __restrict__ h,
                                             const float* __restrict__ bias,
                                             const int* __restrict__ off, const int* __restrict__ csrc,
                                             const float* __restrict__ ccoef, const float* __restrict__ dinv,
                                             float* __restrict__ out) {
    int node = (blockIdx.x * 256 + threadIdx.x) >> 6;
    int lane = threadIdx.x & 63;
    if (node >= N_NODES) return;
    float di = dinv[node];
    float selfc = di * di;
    ushort4 hv = ((const ushort4*)(h + (size_t)node * HIDDEN))[lane];
    float4 bv = ((const float4*)bias)[lane];
    float4 acc = make_float4(bv.x + bf2f(hv.x) * selfc, bv.y + bf2f(hv.y) * selfc,
                             bv.z + bf2f(hv.z) * selfc, bv.w + bf2f(hv.w) * selfc);
    int e = off[node], e1 = off[node + 1];
    for (; e + 1 < e1; e += 2) {
        int s0 = csrc[e], s1 = csrc[e + 1];
        float c0 = ccoef[e], c1 = ccoef[e + 1];
        ushort4 v0 = ((const ushort4*)(h + (size_t)s0 * HIDDEN))[lane];
        ushort4 v1 = ((const ushort4*)(h + (size_t)s1 * HIDDEN))[lane];
        acc.x += c0 * bf2f(v0.x) + c1 * bf2f(v1.x);
        acc.y += c0 * bf2f(v0.y) + c1 * bf2f(v1.y);
        acc.z += c0 * bf2f(v0.z) + c1 * bf2f(v1.z);
        acc.w += c0 * bf2f(v0.w) + c1 * bf2f(v1.w);
    }
    if (e < e1) {
        int s0 = csrc[e]; float c0 = ccoef[e];
        ushort4 v0 = ((const ushort4*)(h + (size_t)s0 * HIDDEN))[lane];
        acc.x += c0 * bf2f(v0.x); acc.y += c0 * bf2f(v0.y);
        acc.z += c0 * bf2f(v0.z); acc.w += c0 * bf2f(v0.w);
    }
    acc.x = acc.x >= 0.f ? acc.x : NEG_SLOPE * acc.x;
    acc.y = acc.y >= 0.f ? acc.y : NEG_SLOPE * acc.y;
    acc.z = acc.z >= 0.f ? acc.z : NEG_SLOPE * acc.z;
    acc.w = acc.w >= 0.f ? acc.w : NEG_SLOPE * acc.w;
    ((float4*)(out + (size_t)node * HIDDEN))[lane] = acc;
}

// ---------------- global mean pool (partial sums + atomics) ----------------
__global__ void k_pool(const float* __restrict__ h, const int* __restrict__ gstart,
                       const int* __restrict__ gcnt, float* __restrict__ pooled) {
    int g = blockIdx.x, chunk = blockIdx.y, t = threadIdx.x;
    int s = gstart[g], c = gcnt[g];
    int i0 = s + (int)(((long long)c * chunk) / 16);
    int i1 = s + (int)(((long long)c * (chunk + 1)) / 16);
    float acc = 0.f;
    for (int i = i0; i < i1; ++i) acc += h[(size_t)i * HIDDEN + t];
    atomicAdd(&pooled[g * HIDDEN + t], acc);
}

// ---------------- classifier head + softmax (one wave per graph) ----------------
__global__ void k_head(const float* __restrict__ pooled, const int* __restrict__ gcnt,
                       const float* __restrict__ Wc, const float* __restrict__ bc,
                       float* __restrict__ out) {
    int g = blockIdx.x; int l = threadIdx.x;  // 64 threads
    float inv = 1.0f / fmaxf((float)gcnt[g], 1.0f);
    float p[4];
#pragma unroll
    for (int i = 0; i < 4; i++) p[i] = pooled[g * HIDDEN + l + i * 64] * inv;
    __shared__ float logits[N_CLASSES];
#pragma unroll
    for (int j = 0; j < N_CLASSES; j++) {
        float s = 0.f;
#pragma unroll
        for (int i = 0; i < 4; i++) s += p[i] * Wc[(l + i * 64) * N_CLASSES + j];
        for (int o = 32; o > 0; o >>= 1) s += __shfl_down(s, o, 64);
        if (l == 0) logits[j] = s + bc[j];
    }
    __syncthreads();
    if (l == 0) {
        float m = logits[0];
        for (int j = 1; j < N_CLASSES; j++) m = fmaxf(m, logits[j]);
        float e[N_CLASSES]; float sum = 0.f;
        for (int j = 0; j < N_CLASSES; j++) { e[j] = expf(logits[j] - m); sum += e[j]; }
        for (int j = 0; j < N_CLASSES; j++) out[g * N_CLASSES + j] = e[j] / sum;
    }
}

extern "C" void kernel_launch(void* const* d_in, const int* in_sizes, int n_in,
                              void* d_out, int out_size, void* d_ws, size_t ws_size,
                              hipStream_t stream) {
    const float* x     = (const float*)d_in[0];
    const int*   edge  = (const int*)d_in[1];
    const int*   batch = (const int*)d_in[2];
    const float* W1 = (const float*)d_in[3];
    const float* b1 = (const float*)d_in[4];
    const float* W2 = (const float*)d_in[5];
    const float* b2 = (const float*)d_in[6];
    const float* W3 = (const float*)d_in[7];
    const float* b3 = (const float*)d_in[8];
    const float* Wc = (const float*)d_in[9];
    const float* bc = (const float*)d_in[10];
    float* out = (float*)d_out;
    const int* srcp = edge;
    const int* dstp = edge + N_EDGES;

    char* ws = (char*)d_ws;
    size_t off = 0;
    auto alloc = [&](size_t bytes) -> char* {
        char* p = ws + off;
        off += (bytes + 255) & ~(size_t)255;
        return p;
    };
    __hip_bfloat16* hA = (__hip_bfloat16*)alloc((size_t)N_NODES * HIDDEN * 2);  // GEMM out (gathered)
    float* hB       = (float*)alloc((size_t)N_NODES * HIDDEN * 4);              // agg out (GEMM in)
    int*   deg_cnt  = (int*)alloc((size_t)N_NODES * 4);
    float* dinv     = (float*)alloc((size_t)N_NODES * 4);
    int*   csr_off  = (int*)alloc((size_t)(N_NODES + 1) * 4);
    int*   cursor   = (int*)alloc((size_t)N_NODES * 4);
    int*   csr_src  = (int*)alloc((size_t)N_EDGES * 4);
    float* csr_coef = (float*)alloc((size_t)N_EDGES * 4);
    int*   gcnt     = (int*)alloc((size_t)N_GRAPHS * 4);
    int*   gstart   = (int*)alloc((size_t)N_GRAPHS * 4);
    float* pooled   = (float*)alloc((size_t)N_GRAPHS * HIDDEN * 4);
    int*   bsum     = (int*)alloc(128 * 4);

    hipMemsetAsync(deg_cnt, 0, (size_t)N_NODES * 4, stream);
    hipMemsetAsync(pooled, 0, (size_t)N_GRAPHS * HIDDEN * 4, stream);

    int eb = (N_EDGES + 255) / 256;
    int nb = (N_NODES + 255) / 256;
    int sblocks = (N_NODES + 1023) / 1024;  // 98

    k_deg_hist<<<eb, 256, 0, stream>>>(dstp, deg_cnt);
    k_graph_bounds<<<1, 64, 0, stream>>>(batch, gstart, gcnt);
    k_dinv<<<nb, 256, 0, stream>>>(deg_cnt, dinv);
    k_scanA<<<sblocks, 256, 0, stream>>>(deg_cnt, csr_off, bsum);
    k_scanB<<<1, 128, 0, stream>>>(bsum, sblocks);
    k_scanC<<<nb, 256, 0, stream>>>(csr_off, bsum, cursor);
    k_fill<<<eb, 256, 0, stream>>>(srcp, dstp, dinv, cursor, csr_src, csr_coef);

    // layer 1
    k_mm1<<<N_NODES, 256, 0, stream>>>(x, W1, hA);
    int aggb = (N_NODES + 3) / 4;
    k_agg<<<aggb, 256, 0, stream>>>(hA, b1, csr_off, csr_src, csr_coef, dinv, hB);
    // layer 2
    dim3 gg((N_NODES + 63) / 64, 4);
    k_gemm256<<<gg, 256, 0, stream>>>(hB, W2, hA, N_NODES);
    k_agg<<<aggb, 256, 0, stream>>>(hA, b2, csr_off, csr_src, csr_coef, dinv, hB);
    // layer 3
    k_gemm256<<<gg, 256, 0, stream>>>(hB, W3, hA, N_NODES);
    k_agg<<<aggb, 256, 0, stream>>>(hA, b3, csr_off, csr_src, csr_coef, dinv, hB);
    // pool + head
    dim3 pg(N_GRAPHS, 16);
    k_pool<<<pg, 256, 0, stream>>>(hB, gstart, gcnt, pooled);
    k_head<<<N_GRAPHS, 64, 0, stream>>>(pooled, gcnt, Wc, bc, out);
}

// Round 4
// 937.576 us; speedup vs baseline: 2.0305x; 1.1437x over previous
//
#include <hip/hip_runtime.h>
#include <hip/hip_bf16.h>
#include <cstdint>
#include <cstddef>

#define N_NODES   100000
#define N_EDGES   1600000
#define N_GRAPHS  64
#define HIDDEN    256
#define N_CLASSES 10
#define NEG_SLOPE 0.01f

typedef __attribute__((ext_vector_type(8))) short bfrag8;   // 8 bf16 (4 VGPRs)
typedef __attribute__((ext_vector_type(4))) float f32x4;    // MFMA C/D

__device__ __forceinline__ float bf2f(unsigned short u) {
    return __uint_as_float(((unsigned int)u) << 16);
}

// ---------------- degree histogram ----------------
__global__ void k_deg_hist(const int* __restrict__ dst, int* __restrict__ cnt) {
    int e = blockIdx.x * 256 + threadIdx.x;
    if (e < N_EDGES) atomicAdd(&cnt[dst[e]], 1);
}

// ---------------- graph boundaries via binary search (batch is sorted) ----------------
__global__ void k_graph_bounds(const int* __restrict__ batch,
                               int* __restrict__ gstart, int* __restrict__ gcnt) {
    int g = threadIdx.x;  // 0..63
    int lo = 0, hi = N_NODES;
    while (lo < hi) { int mid = (lo + hi) >> 1; if (batch[mid] < g) lo = mid + 1; else hi = mid; }
    __shared__ int sh[N_GRAPHS + 1];
    sh[g] = lo;
    if (g == 0) sh[N_GRAPHS] = N_NODES;
    __syncthreads();
    gstart[g] = sh[g];
    gcnt[g]   = sh[g + 1] - sh[g];
}

__global__ void k_dinv(const int* __restrict__ cnt, float* __restrict__ dinv) {
    int i = blockIdx.x * 256 + threadIdx.x;
    if (i < N_NODES) dinv[i] = rsqrtf((float)cnt[i] + 1.0f);
}

// ---------------- exclusive scan of degree counts (CSR offsets) ----------------
__global__ void k_scanA(const int* __restrict__ cnt, int* __restrict__ out, int* __restrict__ bsum) {
    __shared__ int sh[256];
    int tid = threadIdx.x;
    int base = blockIdx.x * 1024 + tid * 4;
    int v[4]; int s = 0;
#pragma unroll
    for (int i = 0; i < 4; i++) { int idx = base + i; v[i] = (idx < N_NODES) ? cnt[idx] : 0; s += v[i]; }
    sh[tid] = s; __syncthreads();
    for (int off = 1; off < 256; off <<= 1) {
        int t = (tid >= off) ? sh[tid - off] : 0;
        __syncthreads();
        sh[tid] += t;
        __syncthreads();
    }
    int excl = sh[tid] - s;
    if (tid == 255) bsum[blockIdx.x] = sh[255];
#pragma unroll
    for (int i = 0; i < 4; i++) { int idx = base + i; if (idx < N_NODES) out[idx] = excl; excl += v[i]; }
}

__global__ void k_scanB(int* __restrict__ bsum, int nb) {
    __shared__ int sh[128];
    int tid = threadIdx.x;
    int v = (tid < nb) ? bsum[tid] : 0;
    sh[tid] = v; __syncthreads();
    for (int off = 1; off < 128; off <<= 1) {
        int t = (tid >= off) ? sh[tid - off] : 0;
        __syncthreads();
        sh[tid] += t;
        __syncthreads();
    }
    if (tid < nb) bsum[tid] = sh[tid] - v;  // exclusive
}

__global__ void k_scanC(int* __restrict__ off_arr, const int* __restrict__ bsum, int* __restrict__ cursor) {
    int i = blockIdx.x * 256 + threadIdx.x;
    if (i < N_NODES) {
        int v = off_arr[i] + bsum[i >> 10];
        off_arr[i] = v;
        cursor[i]  = v;
        if (i == 0) off_arr[N_NODES] = N_EDGES;
    }
}

// ---------------- CSR fill (sorted by dst) + per-edge coefficient ----------------
__global__ void k_fill(const int* __restrict__ src, const int* __restrict__ dst,
                       const float* __restrict__ dinv, int* __restrict__ cursor,
                       int* __restrict__ csrc, float* __restrict__ ccoef) {
    int e = blockIdx.x * 256 + threadIdx.x;
    if (e < N_EDGES) {
        int d = dst[e], s = src[e];
        int p = atomicAdd(&cursor[d], 1);
        csrc[p]  = s;
        ccoef[p] = dinv[s] * dinv[d];
    }
}

// ---------------- weight prep: W[k][n] fp32 -> Wt[n][k] bf16 ----------------
__global__ void k_wprep(const float* __restrict__ W, __hip_bfloat16* __restrict__ Wt) {
    int n = blockIdx.x; int k = threadIdx.x;  // 256 x 256
    Wt[n * HIDDEN + k] = __float2bfloat16(W[k * HIDDEN + n]);
}

// ---------------- layer-1 matmul: [N,3] @ [3,256], bf16 output ----------------
__global__ void k_mm1(const float* __restrict__ x, const float* __restrict__ W1,
                      __hip_bfloat16* __restrict__ out) {
    int node = blockIdx.x; int c = threadIdx.x;
    float x0 = x[node * 3 + 0], x1 = x[node * 3 + 1], x2 = x[node * 3 + 2];
    float v = x0 * W1[c] + x1 * W1[HIDDEN + c] + x2 * W1[2 * HIDDEN + c];
    out[(size_t)node * HIDDEN + c] = __float2bfloat16(v);
}

// ---------------- MFMA GEMM: C[M,256] = A[M,256] x W  (A bf16, Wt[n][k] bf16, C bf16) ----------------
// one wave per 16-row strip, full N=256 per wave (A read exactly once)
// A-frag: A[m=lane&15][k=quad*8+j]; B-frag: B[k=quad*8+j][n=lane&15] = Wt[n][k...]
// C/D:    col=lane&15, row=quad*4+reg
__global__ __launch_bounds__(256) void k_gemm_mfma(const __hip_bfloat16* __restrict__ A,
                                                   const __hip_bfloat16* __restrict__ Wt,
                                                   __hip_bfloat16* __restrict__ C, int M) {
    int wave = (blockIdx.x * 256 + threadIdx.x) >> 6;
    int m0 = wave * 16;
    if (m0 >= M) return;
    int lane = threadIdx.x & 63;
    int quad = lane >> 4;
    int r    = lane & 15;
    const short* Ab = (const short*)A  + (size_t)(m0 + r) * HIDDEN + quad * 8;
    const short* Bb = (const short*)Wt + (size_t)r * HIDDEN + quad * 8;
    f32x4 acc[16];
#pragma unroll
    for (int i = 0; i < 16; i++) acc[i] = (f32x4){0.f, 0.f, 0.f, 0.f};
    for (int k0 = 0; k0 < HIDDEN; k0 += 32) {
        bfrag8 a = *(const bfrag8*)(Ab + k0);
#pragma unroll
        for (int nt = 0; nt < 16; nt++) {
            bfrag8 b = *(const bfrag8*)(Bb + (size_t)nt * 16 * HIDDEN + k0);
            acc[nt] = __builtin_amdgcn_mfma_f32_16x16x32_bf16(a, b, acc[nt], 0, 0, 0);
        }
    }
#pragma unroll
    for (int nt = 0; nt < 16; nt++) {
#pragma unroll
        for (int i = 0; i < 4; i++) {
            int row = m0 + quad * 4 + i;
            C[(size_t)row * HIDDEN + nt * 16 + r] = __float2bfloat16(acc[nt][i]);
        }
    }
}

// ---------------- fused aggregation + self-loop + bias + leaky-relu ----------------
// one wave per node; h rows are bf16 (512 B); lane = 4 contiguous bf16 (8 B); bf16 output
__global__ __launch_bounds__(256) void k_agg(const __hip_bfloat16* __restrict__ h,
                                             const float* __restrict__ bias,
                                             const int* __restrict__ off, const int* __restrict__ csrc,
                                             const float* __restrict__ ccoef, const float* __restrict__ dinv,
                                             __hip_bfloat16* __restrict__ out) {
    int node = (blockIdx.x * 256 + threadIdx.x) >> 6;
    int lane = threadIdx.x & 63;
    if (node >= N_NODES) return;
    float di = dinv[node];
    float selfc = di * di;
    ushort4 hv = ((const ushort4*)(h + (size_t)node * HIDDEN))[lane];
    float4 bv = ((const float4*)bias)[lane];
    float4 acc = make_float4(bv.x + bf2f(hv.x) * selfc, bv.y + bf2f(hv.y) * selfc,
                             bv.z + bf2f(hv.z) * selfc, bv.w + bf2f(hv.w) * selfc);
    int e = off[node], e1 = off[node + 1];
    for (; e + 1 < e1; e += 2) {
        int s0 = csrc[e], s1 = csrc[e + 1];
        float c0 = ccoef[e], c1 = ccoef[e + 1];
        ushort4 v0 = ((const ushort4*)(h + (size_t)s0 * HIDDEN))[lane];
        ushort4 v1 = ((const ushort4*)(h + (size_t)s1 * HIDDEN))[lane];
        acc.x += c0 * bf2f(v0.x) + c1 * bf2f(v1.x);
        acc.y += c0 * bf2f(v0.y) + c1 * bf2f(v1.y);
        acc.z += c0 * bf2f(v0.z) + c1 * bf2f(v1.z);
        acc.w += c0 * bf2f(v0.w) + c1 * bf2f(v1.w);
    }
    if (e < e1) {
        int s0 = csrc[e]; float c0 = ccoef[e];
        ushort4 v0 = ((const ushort4*)(h + (size_t)s0 * HIDDEN))[lane];
        acc.x += c0 * bf2f(v0.x); acc.y += c0 * bf2f(v0.y);
        acc.z += c0 * bf2f(v0.z); acc.w += c0 * bf2f(v0.w);
    }
    acc.x = acc.x >= 0.f ? acc.x : NEG_SLOPE * acc.x;
    acc.y = acc.y >= 0.f ? acc.y : NEG_SLOPE * acc.y;
    acc.z = acc.z >= 0.f ? acc.z : NEG_SLOPE * acc.z;
    acc.w = acc.w >= 0.f ? acc.w : NEG_SLOPE * acc.w;
    __hip_bfloat16 pk[4] = {__float2bfloat16(acc.x), __float2bfloat16(acc.y),
                            __float2bfloat16(acc.z), __float2bfloat16(acc.w)};
    *(uint2*)(out + (size_t)node * HIDDEN + lane * 4) = *(uint2*)pk;
}

// ---------------- global mean pool (partial sums + atomics), bf16 input ----------------
__global__ void k_pool(const __hip_bfloat16* __restrict__ h, const int* __restrict__ gstart,
                       const int* __restrict__ gcnt, float* __restrict__ pooled) {
    int g = blockIdx.x, chunk = blockIdx.y, t = threadIdx.x;
    int s = gstart[g], c = gcnt[g];
    int i0 = s + (int)(((long long)c * chunk) / 16);
    int i1 = s + (int)(((long long)c * (chunk + 1)) / 16);
    const unsigned short* hu = (const unsigned short*)h;
    float acc = 0.f;
    for (int i = i0; i < i1; ++i) acc += bf2f(hu[(size_t)i * HIDDEN + t]);
    atomicAdd(&pooled[g * HIDDEN + t], acc);
}

// ---------------- classifier head + softmax (one wave per graph) ----------------
__global__ void k_head(const float* __restrict__ pooled, const int* __restrict__ gcnt,
                       const float* __restrict__ Wc, const float* __restrict__ bc,
                       float* __restrict__ out) {
    int g = blockIdx.x; int l = threadIdx.x;  // 64 threads
    float inv = 1.0f / fmaxf((float)gcnt[g], 1.0f);
    float p[4];
#pragma unroll
    for (int i = 0; i < 4; i++) p[i] = pooled[g * HIDDEN + l + i * 64] * inv;
    __shared__ float logits[N_CLASSES];
#pragma unroll
    for (int j = 0; j < N_CLASSES; j++) {
        float s = 0.f;
#pragma unroll
        for (int i = 0; i < 4; i++) s += p[i] * Wc[(l + i * 64) * N_CLASSES + j];
        for (int o = 32; o > 0; o >>= 1) s += __shfl_down(s, o, 64);
        if (l == 0) logits[j] = s + bc[j];
    }
    __syncthreads();
    if (l == 0) {
        float m = logits[0];
        for (int j = 1; j < N_CLASSES; j++) m = fmaxf(m, logits[j]);
        float e[N_CLASSES]; float sum = 0.f;
        for (int j = 0; j < N_CLASSES; j++) { e[j] = expf(logits[j] - m); sum += e[j]; }
        for (int j = 0; j < N_CLASSES; j++) out[g * N_CLASSES + j] = e[j] / sum;
    }
}

extern "C" void kernel_launch(void* const* d_in, const int* in_sizes, int n_in,
                              void* d_out, int out_size, void* d_ws, size_t ws_size,
                              hipStream_t stream) {
    const float* x     = (const float*)d_in[0];
    const int*   edge  = (const int*)d_in[1];
    const int*   batch = (const int*)d_in[2];
    const float* W1 = (const float*)d_in[3];
    const float* b1 = (const float*)d_in[4];
    const float* W2 = (const float*)d_in[5];
    const float* b2 = (const float*)d_in[6];
    const float* W3 = (const float*)d_in[7];
    const float* b3 = (const float*)d_in[8];
    const float* Wc = (const float*)d_in[9];
    const float* bc = (const float*)d_in[10];
    float* out = (float*)d_out;
    const int* srcp = edge;
    const int* dstp = edge + N_EDGES;

    char* ws = (char*)d_ws;
    size_t off = 0;
    auto alloc = [&](size_t bytes) -> char* {
        char* p = ws + off;
        off += (bytes + 255) & ~(size_t)255;
        return p;
    };
    __hip_bfloat16* hA  = (__hip_bfloat16*)alloc((size_t)N_NODES * HIDDEN * 2);  // GEMM out (gathered)
    __hip_bfloat16* hB  = (__hip_bfloat16*)alloc((size_t)N_NODES * HIDDEN * 2);  // agg out (GEMM in)
    __hip_bfloat16* Wt2 = (__hip_bfloat16*)alloc((size_t)HIDDEN * HIDDEN * 2);
    __hip_bfloat16* Wt3 = (__hip_bfloat16*)alloc((size_t)HIDDEN * HIDDEN * 2);
    int*   deg_cnt  = (int*)alloc((size_t)N_NODES * 4);
    float* dinv     = (float*)alloc((size_t)N_NODES * 4);
    int*   csr_off  = (int*)alloc((size_t)(N_NODES + 1) * 4);
    int*   cursor   = (int*)alloc((size_t)N_NODES * 4);
    int*   csr_src  = (int*)alloc((size_t)N_EDGES * 4);
    float* csr_coef = (float*)alloc((size_t)N_EDGES * 4);
    int*   gcnt     = (int*)alloc((size_t)N_GRAPHS * 4);
    int*   gstart   = (int*)alloc((size_t)N_GRAPHS * 4);
    float* pooled   = (float*)alloc((size_t)N_GRAPHS * HIDDEN * 4);
    int*   bsum     = (int*)alloc(128 * 4);

    hipMemsetAsync(deg_cnt, 0, (size_t)N_NODES * 4, stream);
    hipMemsetAsync(pooled, 0, (size_t)N_GRAPHS * HIDDEN * 4, stream);

    int eb = (N_EDGES + 255) / 256;
    int nb = (N_NODES + 255) / 256;
    int sblocks = (N_NODES + 1023) / 1024;  // 98

    k_deg_hist<<<eb, 256, 0, stream>>>(dstp, deg_cnt);
    k_graph_bounds<<<1, 64, 0, stream>>>(batch, gstart, gcnt);
    k_dinv<<<nb, 256, 0, stream>>>(deg_cnt, dinv);
    k_scanA<<<sblocks, 256, 0, stream>>>(deg_cnt, csr_off, bsum);
    k_scanB<<<1, 128, 0, stream>>>(bsum, sblocks);
    k_scanC<<<nb, 256, 0, stream>>>(csr_off, bsum, cursor);
    k_fill<<<eb, 256, 0, stream>>>(srcp, dstp, dinv, cursor, csr_src, csr_coef);
    k_wprep<<<HIDDEN, HIDDEN, 0, stream>>>(W2, Wt2);
    k_wprep<<<HIDDEN, HIDDEN, 0, stream>>>(W3, Wt3);

    // layer 1
    k_mm1<<<N_NODES, 256, 0, stream>>>(x, W1, hA);
    int aggb = (N_NODES + 3) / 4;
    k_agg<<<aggb, 256, 0, stream>>>(hA, b1, csr_off, csr_src, csr_coef, dinv, hB);
    // layer 2
    int gemmb = (N_NODES / 16 + 3) / 4;  // 4 waves/block, 16 rows/wave
    k_gemm_mfma<<<gemmb, 256, 0, stream>>>(hB, Wt2, hA, N_NODES);
    k_agg<<<aggb, 256, 0, stream>>>(hA, b2, csr_off, csr_src, csr_coef, dinv, hB);
    // layer 3
    k_gemm_mfma<<<gemmb, 256, 0, stream>>>(hB, Wt3, hA, N_NODES);
    k_agg<<<aggb, 256, 0, stream>>>(hA, b3, csr_off, csr_src, csr_coef, dinv, hB);
    // pool + head
    dim3 pg(N_GRAPHS, 16);
    k_pool<<<pg, 256, 0, stream>>>(hB, gstart, gcnt, pooled);
    k_head<<<N_GRAPHS, 64, 0, stream>>>(pooled, gcnt, Wc, bc, out);
}

// Round 5
// 779.167 us; speedup vs baseline: 2.4433x; 1.2033x over previous
//
#include <hip/hip_runtime.h>
#include <hip/hip_bf16.h>
#include <cstdint>
#include <cstddef>

#define N_NODES   100000
#define N_EDGES   1600000
#define N_GRAPHS  64
#define HIDDEN    256
#define N_CLASSES 10
#define NEG_SLOPE 0.01f

typedef __attribute__((ext_vector_type(8))) short bfrag8;   // 8 bf16 (4 VGPRs)
typedef __attribute__((ext_vector_type(4))) float f32x4;    // MFMA C/D

__device__ __forceinline__ float bf2f(unsigned short u) {
    return __uint_as_float(((unsigned int)u) << 16);
}

// ---------------- degree histogram ----------------
__global__ void k_deg_hist(const int* __restrict__ dst, int* __restrict__ cnt) {
    int e = blockIdx.x * 256 + threadIdx.x;
    if (e < N_EDGES) atomicAdd(&cnt[dst[e]], 1);
}

// ---------------- graph boundaries via binary search (batch is sorted) ----------------
__global__ void k_graph_bounds(const int* __restrict__ batch,
                               int* __restrict__ gstart, int* __restrict__ gcnt) {
    int g = threadIdx.x;  // 0..63
    int lo = 0, hi = N_NODES;
    while (lo < hi) { int mid = (lo + hi) >> 1; if (batch[mid] < g) lo = mid + 1; else hi = mid; }
    __shared__ int sh[N_GRAPHS + 1];
    sh[g] = lo;
    if (g == 0) sh[N_GRAPHS] = N_NODES;
    __syncthreads();
    gstart[g] = sh[g];
    gcnt[g]   = sh[g + 1] - sh[g];
}

__global__ void k_dinv(const int* __restrict__ cnt, float* __restrict__ dinv) {
    int i = blockIdx.x * 256 + threadIdx.x;
    if (i < N_NODES) dinv[i] = rsqrtf((float)cnt[i] + 1.0f);
}

// ---------------- exclusive scan of PADDED degree counts (CSR offsets) ----------------
// degrees rounded up to multiple of 4 so the agg loop is exact int4-wide
__global__ void k_scanA(const int* __restrict__ cnt, int* __restrict__ out, int* __restrict__ bsum) {
    __shared__ int sh[256];
    int tid = threadIdx.x;
    int base = blockIdx.x * 1024 + tid * 4;
    int v[4]; int s = 0;
#pragma unroll
    for (int i = 0; i < 4; i++) {
        int idx = base + i;
        v[i] = (idx < N_NODES) ? ((cnt[idx] + 3) & ~3) : 0;
        s += v[i];
    }
    sh[tid] = s; __syncthreads();
    for (int off = 1; off < 256; off <<= 1) {
        int t = (tid >= off) ? sh[tid - off] : 0;
        __syncthreads();
        sh[tid] += t;
        __syncthreads();
    }
    int excl = sh[tid] - s;
    if (tid == 255) bsum[blockIdx.x] = sh[255];
#pragma unroll
    for (int i = 0; i < 4; i++) { int idx = base + i; if (idx < N_NODES) out[idx] = excl; excl += v[i]; }
}

__global__ void k_scanB(int* __restrict__ bsum, int nb) {
    __shared__ int sh[128];
    int tid = threadIdx.x;
    int v = (tid < nb) ? bsum[tid] : 0;
    sh[tid] = v; __syncthreads();
    for (int off = 1; off < 128; off <<= 1) {
        int t = (tid >= off) ? sh[tid - off] : 0;
        __syncthreads();
        sh[tid] += t;
        __syncthreads();
    }
    if (tid < nb) bsum[tid] = sh[tid] - v;  // exclusive
}

__global__ void k_scanC(int* __restrict__ off_arr, const int* __restrict__ bsum,
                        int* __restrict__ cursor, const int* __restrict__ cnt) {
    int i = blockIdx.x * 256 + threadIdx.x;
    if (i < N_NODES) {
        int v = off_arr[i] + bsum[i >> 10];
        off_arr[i] = v;
        cursor[i]  = v;
        if (i == N_NODES - 1) off_arr[N_NODES] = v + ((cnt[i] + 3) & ~3);
    }
}

// zero the padding slots (between real degree and padded degree)
__global__ void k_padfill(const int* __restrict__ off, const int* __restrict__ cnt,
                          int* __restrict__ csrc, float* __restrict__ ccoef) {
    int i = blockIdx.x * 256 + threadIdx.x;
    if (i < N_NODES) {
        int p  = off[i] + cnt[i];
        int p1 = off[i + 1];
        for (; p < p1; ++p) { csrc[p] = 0; ccoef[p] = 0.f; }
    }
}

// ---------------- CSR fill (sorted by dst) + per-edge coefficient ----------------
__global__ void k_fill(const int* __restrict__ src, const int* __restrict__ dst,
                       const float* __restrict__ dinv, int* __restrict__ cursor,
                       int* __restrict__ csrc, float* __restrict__ ccoef) {
    int e = blockIdx.x * 256 + threadIdx.x;
    if (e < N_EDGES) {
        int d = dst[e], s = src[e];
        int p = atomicAdd(&cursor[d], 1);
        csrc[p]  = s;
        ccoef[p] = dinv[s] * dinv[d];
    }
}

// ---------------- weight prep: W[k][n] fp32 -> Wt[n][k] bf16 ----------------
__global__ void k_wprep(const float* __restrict__ W, __hip_bfloat16* __restrict__ Wt) {
    int n = blockIdx.x; int k = threadIdx.x;  // 256 x 256
    Wt[n * HIDDEN + k] = __float2bfloat16(W[k * HIDDEN + n]);
}

// ---------------- layer-1 reassociated: ax = Norm * x  (3 features, exact) ----------------
__global__ void k_agg3(const float* __restrict__ x, const int* __restrict__ off,
                       const int* __restrict__ csrc, const float* __restrict__ ccoef,
                       const float* __restrict__ dinv, float4* __restrict__ ax) {
    int i = blockIdx.x * 256 + threadIdx.x;
    if (i >= N_NODES) return;
    float di = dinv[i];
    float selfc = di * di;
    float a0 = x[i * 3 + 0] * selfc, a1 = x[i * 3 + 1] * selfc, a2 = x[i * 3 + 2] * selfc;
    int e = off[i], e1 = off[i + 1];
    for (; e < e1; e += 4) {
        int4   ss = *(const int4*)(csrc + e);
        float4 cc = *(const float4*)(ccoef + e);
        a0 += cc.x * x[ss.x * 3 + 0] + cc.y * x[ss.y * 3 + 0] + cc.z * x[ss.z * 3 + 0] + cc.w * x[ss.w * 3 + 0];
        a1 += cc.x * x[ss.x * 3 + 1] + cc.y * x[ss.y * 3 + 1] + cc.z * x[ss.z * 3 + 1] + cc.w * x[ss.w * 3 + 1];
        a2 += cc.x * x[ss.x * 3 + 2] + cc.y * x[ss.y * 3 + 2] + cc.z * x[ss.z * 3 + 2] + cc.w * x[ss.w * 3 + 2];
    }
    ax[i] = make_float4(a0, a1, a2, 0.f);
}

// h1 = leaky(ax @ W1 + b1), bf16 out
__global__ void k_l1(const float4* __restrict__ ax, const float* __restrict__ W1,
                     const float* __restrict__ b1, __hip_bfloat16* __restrict__ out) {
    int node = blockIdx.x; int c = threadIdx.x;
    float4 a = ax[node];
    float v = a.x * W1[c] + a.y * W1[HIDDEN + c] + a.z * W1[2 * HIDDEN + c] + b1[c];
    v = v >= 0.f ? v : NEG_SLOPE * v;
    out[(size_t)node * HIDDEN + c] = __float2bfloat16(v);
}

// ---------------- MFMA GEMM with LDS-staged Wt ----------------
// block = 256 thr (4 waves), tile = 64 rows x 256 cols; Wt chunk (256n x 32k) in LDS,
// row stride 40 shorts (80 B) -> conflict-free frag reads.
// A-frag: A[m=lane&15][k=quad*8+j]; B-frag: B[k=quad*8+j][n=lane&15]; C/D: col=r, row=quad*4+reg
__global__ __launch_bounds__(256) void k_gemm_mfma(const __hip_bfloat16* __restrict__ A,
                                                   const __hip_bfloat16* __restrict__ Wt,
                                                   __hip_bfloat16* __restrict__ C, int M) {
    __shared__ short Bs[256 * 40];  // 20 KB
    int tid = threadIdx.x;
    int wv = tid >> 6, lane = tid & 63;
    int quad = lane >> 4, r = lane & 15;
    int m0 = blockIdx.x * 64 + wv * 16;
    int arow = m0 + r; if (arow >= M) arow = M - 1;
    const short* Ab = (const short*)A + (size_t)arow * HIDDEN + quad * 8;

    bfrag8 af[8];
#pragma unroll
    for (int c = 0; c < 8; ++c) af[c] = *(const bfrag8*)(Ab + c * 32);

    f32x4 acc[16];
#pragma unroll
    for (int i = 0; i < 16; i++) acc[i] = (f32x4){0.f, 0.f, 0.f, 0.f};

    const float4* wsrc = (const float4*)((const short*)Wt + (size_t)tid * HIDDEN);  // row n=tid
    float4 st[4];
#pragma unroll
    for (int i = 0; i < 4; ++i) st[i] = wsrc[i];  // chunk 0

#pragma unroll
    for (int c = 0; c < 8; ++c) {
        __syncthreads();
        float4* bdst = (float4*)(Bs + tid * 40);
#pragma unroll
        for (int i = 0; i < 4; ++i) bdst[i] = st[i];
        __syncthreads();
        if (c < 7) {
#pragma unroll
            for (int i = 0; i < 4; ++i) st[i] = wsrc[(c + 1) * 4 + i];
        }
#pragma unroll
        for (int nt = 0; nt < 16; ++nt) {
            bfrag8 b = *(const bfrag8*)(Bs + (nt * 16 + r) * 40 + quad * 8);
            acc[nt] = __builtin_amdgcn_mfma_f32_16x16x32_bf16(af[c], b, acc[nt], 0, 0, 0);
        }
    }
#pragma unroll
    for (int nt = 0; nt < 16; ++nt) {
#pragma unroll
        for (int i = 0; i < 4; ++i) {
            int row = m0 + quad * 4 + i;
            if (row < M) C[(size_t)row * HIDDEN + nt * 16 + r] = __float2bfloat16(acc[nt][i]);
        }
    }
}

// ---------------- fused aggregation + self-loop + bias + leaky-relu ----------------
// one wave per node; bf16 rows; padded CSR -> exact 4-wide loop, 4 gathers in flight
__global__ __launch_bounds__(256) void k_agg(const __hip_bfloat16* __restrict__ h,
                                             const float* __restrict__ bias,
                                             const int* __restrict__ off, const int* __restrict__ csrc,
                                             const float* __restrict__ ccoef, const float* __restrict__ dinv,
                                             __hip_bfloat16* __restrict__ out) {
    int node = (blockIdx.x * 256 + threadIdx.x) >> 6;
    int lane = threadIdx.x & 63;
    if (node >= N_NODES) return;
    float di = dinv[node];
    float selfc = di * di;
    ushort4 hv = ((const ushort4*)(h + (size_t)node * HIDDEN))[lane];
    float4 bv = ((const float4*)bias)[lane];
    float4 acc = make_float4(bv.x + bf2f(hv.x) * selfc, bv.y + bf2f(hv.y) * selfc,
                             bv.z + bf2f(hv.z) * selfc, bv.w + bf2f(hv.w) * selfc);
    int e = off[node], e1 = off[node + 1];
    for (; e < e1; e += 4) {
        int4   ss = *(const int4*)(csrc + e);
        float4 cc = *(const float4*)(ccoef + e);
        ushort4 v0 = ((const ushort4*)(h + (size_t)ss.x * HIDDEN))[lane];
        ushort4 v1 = ((const ushort4*)(h + (size_t)ss.y * HIDDEN))[lane];
        ushort4 v2 = ((const ushort4*)(h + (size_t)ss.z * HIDDEN))[lane];
        ushort4 v3 = ((const ushort4*)(h + (size_t)ss.w * HIDDEN))[lane];
        acc.x += cc.x * bf2f(v0.x) + cc.y * bf2f(v1.x) + cc.z * bf2f(v2.x) + cc.w * bf2f(v3.x);
        acc.y += cc.x * bf2f(v0.y) + cc.y * bf2f(v1.y) + cc.z * bf2f(v2.y) + cc.w * bf2f(v3.y);
        acc.z += cc.x * bf2f(v0.z) + cc.y * bf2f(v1.z) + cc.z * bf2f(v2.z) + cc.w * bf2f(v3.z);
        acc.w += cc.x * bf2f(v0.w) + cc.y * bf2f(v1.w) + cc.z * bf2f(v2.w) + cc.w * bf2f(v3.w);
    }
    acc.x = acc.x >= 0.f ? acc.x : NEG_SLOPE * acc.x;
    acc.y = acc.y >= 0.f ? acc.y : NEG_SLOPE * acc.y;
    acc.z = acc.z >= 0.f ? acc.z : NEG_SLOPE * acc.z;
    acc.w = acc.w >= 0.f ? acc.w : NEG_SLOPE * acc.w;
    __hip_bfloat16 pk[4] = {__float2bfloat16(acc.x), __float2bfloat16(acc.y),
                            __float2bfloat16(acc.z), __float2bfloat16(acc.w)};
    *(uint2*)(out + (size_t)node * HIDDEN + lane * 4) = *(uint2*)pk;
}

// ---------------- global mean pool (partial sums + atomics), bf16 input ----------------
__global__ void k_pool(const __hip_bfloat16* __restrict__ h, const int* __restrict__ gstart,
                       const int* __restrict__ gcnt, float* __restrict__ pooled) {
    int g = blockIdx.x, chunk = blockIdx.y, t = threadIdx.x;
    int s = gstart[g], c = gcnt[g];
    int i0 = s + (int)(((long long)c * chunk) / 16);
    int i1 = s + (int)(((long long)c * (chunk + 1)) / 16);
    const unsigned short* hu = (const unsigned short*)h;
    float acc = 0.f;
    for (int i = i0; i < i1; ++i) acc += bf2f(hu[(size_t)i * HIDDEN + t]);
    atomicAdd(&pooled[g * HIDDEN + t], acc);
}

// ---------------- classifier head + softmax (one wave per graph) ----------------
__global__ void k_head(const float* __restrict__ pooled, const int* __restrict__ gcnt,
                       const float* __restrict__ Wc, const float* __restrict__ bc,
                       float* __restrict__ out) {
    int g = blockIdx.x; int l = threadIdx.x;  // 64 threads
    float inv = 1.0f / fmaxf((float)gcnt[g], 1.0f);
    float p[4];
#pragma unroll
    for (int i = 0; i < 4; i++) p[i] = pooled[g * HIDDEN + l + i * 64] * inv;
    __shared__ float logits[N_CLASSES];
#pragma unroll
    for (int j = 0; j < N_CLASSES; j++) {
        float s = 0.f;
#pragma unroll
        for (int i = 0; i < 4; i++) s += p[i] * Wc[(l + i * 64) * N_CLASSES + j];
        for (int o = 32; o > 0; o >>= 1) s += __shfl_down(s, o, 64);
        if (l == 0) logits[j] = s + bc[j];
    }
    __syncthreads();
    if (l == 0) {
        float m = logits[0];
        for (int j = 1; j < N_CLASSES; j++) m = fmaxf(m, logits[j]);
        float e[N_CLASSES]; float sum = 0.f;
        for (int j = 0; j < N_CLASSES; j++) { e[j] = expf(logits[j] - m); sum += e[j]; }
        for (int j = 0; j < N_CLASSES; j++) out[g * N_CLASSES + j] = e[j] / sum;
    }
}

extern "C" void kernel_launch(void* const* d_in, const int* in_sizes, int n_in,
                              void* d_out, int out_size, void* d_ws, size_t ws_size,
                              hipStream_t stream) {
    const float* x     = (const float*)d_in[0];
    const int*   edge  = (const int*)d_in[1];
    const int*   batch = (const int*)d_in[2];
    const float* W1 = (const float*)d_in[3];
    const float* b1 = (const float*)d_in[4];
    const float* W2 = (const float*)d_in[5];
    const float* b2 = (const float*)d_in[6];
    const float* W3 = (const float*)d_in[7];
    const float* b3 = (const float*)d_in[8];
    const float* Wc = (const float*)d_in[9];
    const float* bc = (const float*)d_in[10];
    float* out = (float*)d_out;
    const int* srcp = edge;
    const int* dstp = edge + N_EDGES;

    const int E_PAD = N_EDGES + 4 * N_NODES;  // capacity incl. padding

    char* ws = (char*)d_ws;
    size_t off = 0;
    auto alloc = [&](size_t bytes) -> char* {
        char* p = ws + off;
        off += (bytes + 255) & ~(size_t)255;
        return p;
    };
    __hip_bfloat16* hA  = (__hip_bfloat16*)alloc((size_t)N_NODES * HIDDEN * 2);
    __hip_bfloat16* hB  = (__hip_bfloat16*)alloc((size_t)N_NODES * HIDDEN * 2);
    __hip_bfloat16* Wt2 = (__hip_bfloat16*)alloc((size_t)HIDDEN * HIDDEN * 2);
    __hip_bfloat16* Wt3 = (__hip_bfloat16*)alloc((size_t)HIDDEN * HIDDEN * 2);
    int*   deg_cnt  = (int*)alloc((size_t)N_NODES * 4);
    float* dinv     = (float*)alloc((size_t)N_NODES * 4);
    int*   csr_off  = (int*)alloc((size_t)(N_NODES + 1) * 4);
    int*   cursor   = (int*)alloc((size_t)N_NODES * 4);
    int*   csr_src  = (int*)alloc((size_t)E_PAD * 4);
    float* csr_coef = (float*)alloc((size_t)E_PAD * 4);
    float4* ax      = (float4*)alloc((size_t)N_NODES * 16);
    int*   gcnt     = (int*)alloc((size_t)N_GRAPHS * 4);
    int*   gstart   = (int*)alloc((size_t)N_GRAPHS * 4);
    float* pooled   = (float*)alloc((size_t)N_GRAPHS * HIDDEN * 4);
    int*   bsum     = (int*)alloc(128 * 4);

    hipMemsetAsync(deg_cnt, 0, (size_t)N_NODES * 4, stream);
    hipMemsetAsync(pooled, 0, (size_t)N_GRAPHS * HIDDEN * 4, stream);

    int eb = (N_EDGES + 255) / 256;
    int nb = (N_NODES + 255) / 256;
    int sblocks = (N_NODES + 1023) / 1024;  // 98

    k_deg_hist<<<eb, 256, 0, stream>>>(dstp, deg_cnt);
    k_graph_bounds<<<1, 64, 0, stream>>>(batch, gstart, gcnt);
    k_dinv<<<nb, 256, 0, stream>>>(deg_cnt, dinv);
    k_scanA<<<sblocks, 256, 0, stream>>>(deg_cnt, csr_off, bsum);
    k_scanB<<<1, 128, 0, stream>>>(bsum, sblocks);
    k_scanC<<<nb, 256, 0, stream>>>(csr_off, bsum, cursor, deg_cnt);
    k_padfill<<<nb, 256, 0, stream>>>(csr_off, deg_cnt, csr_src, csr_coef);
    k_fill<<<eb, 256, 0, stream>>>(srcp, dstp, dinv, cursor, csr_src, csr_coef);
    k_wprep<<<HIDDEN, HIDDEN, 0, stream>>>(W2, Wt2);
    k_wprep<<<HIDDEN, HIDDEN, 0, stream>>>(W3, Wt3);

    // layer 1 (reassociated): ax = Norm*x; h1 = leaky(ax @ W1 + b1)
    k_agg3<<<nb, 256, 0, stream>>>(x, csr_off, csr_src, csr_coef, dinv, ax);
    k_l1<<<N_NODES, 256, 0, stream>>>(ax, W1, b1, hA);

    int aggb  = (N_NODES + 3) / 4;
    int gemmb = (N_NODES + 63) / 64;
    // layer 2
    k_gemm_mfma<<<gemmb, 256, 0, stream>>>(hA, Wt2, hB, N_NODES);
    k_agg<<<aggb, 256, 0, stream>>>(hB, b2, csr_off, csr_src, csr_coef, dinv, hA);
    // layer 3
    k_gemm_mfma<<<gemmb, 256, 0, stream>>>(hA, Wt3, hB, N_NODES);
    k_agg<<<aggb, 256, 0, stream>>>(hB, b3, csr_off, csr_src, csr_coef, dinv, hA);
    // pool + head
    dim3 pg(N_GRAPHS, 16);
    k_pool<<<pg, 256, 0, stream>>>(hA, gstart, gcnt, pooled);
    k_head<<<N_GRAPHS, 64, 0, stream>>>(pooled, gcnt, Wc, bc, out);
}